// Round 10
// baseline (119.747 us; speedup 1.0000x reference)
//
#include <hip/hip_runtime.h>
#include <hip/hip_fp16.h>
#include <hip/hip_cooperative_groups.h>

namespace cg = cooperative_groups;

#define NATOM 8192
#define FR    128
#define NSEG  64
#define PB    256     // fallback pair-kernel blocks
#define PT    1024    // fallback pair-kernel threads
#define PPT   16      // pairs per thread (per pass)

typedef _Float16 v8h __attribute__((ext_vector_type(8)));
typedef _Float16 v4h __attribute__((ext_vector_type(4)));
typedef float    v4f __attribute__((ext_vector_type(4)));

__device__ __forceinline__ float fast_tanh(float x)
{
    float t = __expf(2.f * x);
    return 1.f - 2.f * __builtin_amdgcn_rcpf(t + 1.f);
}

__device__ __forceinline__ float pair_e(const float4* atomd, int ia, int ib)
{
    float4 A = atomd[ia], B = atomd[ib];
    float dx = A.x - B.x, dy = A.y - B.y, dz = A.z - B.z;
    float D2 = fmaf(dx, dx, fmaf(dy, dy, dz * dz));
    float inv = __builtin_amdgcn_rcpf(D2);
    float inv3 = inv * inv * inv;
    __half2 ha = __builtin_bit_cast(__half2, A.w);
    __half2 hb = __builtin_bit_cast(__half2, B.w);
    float pp = __low2float(ha) * __low2float(hb);    // (sig_i*sig_j)^1.5
    float qq = __high2float(ha) * __high2float(hb);  // eps_mixed
    float s6 = pp * pp * inv3;                       // (sig_i*sig_j)^3 / D2^3
    return 4.f * qq * (s6 * s6 - s6);
}

// ================= single cooperative kernel: all 4 phases =================
// 256 blocks x 512 thr, 132 KB dynamic LDS -> 1 block/CU, all co-resident.
// Phase P = weight split+transpose (round-7 k_prep mapping; blocks 0-95 active)
// Phase M = round-9-verified 32-atom MFMA MLP body
// Phase R = round-8-verified pair body, 2 passes x 16 pairs/thread
// Phase F = block 0 deterministic reduce
__global__ __launch_bounds__(512) void k_all(
    const float* __restrict__ r, const float* __restrict__ xyz,
    const int* __restrict__ pairs, const int* __restrict__ num_pairs,
    const float* __restrict__ w1s, const float* __restrict__ b1s,
    const float* __restrict__ w2s, const float* __restrict__ b2s,
    const float* __restrict__ w3s, const float* __restrict__ b3s,
    const float* __restrict__ w1e, const float* __restrict__ b1e,
    const float* __restrict__ w2e, const float* __restrict__ b2e,
    const float* __restrict__ w3e, const float* __restrict__ b3e,
    _Float16* __restrict__ planes, float4* __restrict__ atomd,
    float* __restrict__ blocksums, float* __restrict__ out, int P)
{
    extern __shared__ char ldsraw[];
    cg::grid_group grid = cg::this_grid();
    const int tid = threadIdx.x;
    const int bid = blockIdx.x;

    // ---------------- phase P: f16 hi/lo split + transpose ----------------
    {
        int i = bid * 512 + tid;
        if (i < 32768) {
            int c = i >> 7, k = i & 127;
            float x = (c < 128) ? w1s[k * 128 + c] : w1e[k * 128 + (c - 128)];
            _Float16 h = (_Float16)x;
            planes[i] = h;
            planes[32768 + i] = (_Float16)((x - (float)h) * 4096.f);
        } else if (i < 49152) {
            int u = i - 32768;
            int c = u >> 7, k = u & 127;
            float x = (c < 64) ? w2s[k * 64 + c] : w2e[k * 64 + (c - 64)];
            _Float16 h = (_Float16)x;
            planes[65536 + u] = h;
            planes[81920 + u] = (_Float16)((x - (float)h) * 4096.f);
        }
    }
    grid.sync();

    // ---------------- phase M: MFMA MLP (32 atoms/block) ----------------
    {
        _Float16* Wh  = (_Float16*)ldsraw;           // phase1: [256][128] swizzled
        _Float16* Wl  = Wh + 32768;
        _Float16* h1h = Wh;                          // phase2: [32][256] swizzled
        _Float16* h1l = Wh + 8192;
        _Float16* W2h = Wh + 16384;                  // [128][128] swizzled
        _Float16* W2l = Wh + 32768;
        float*    mArr = (float*)(ldsraw + 131072);  // [4][32]

        const int a0  = bid * 32;
        const int l = tid & 63, wv = tid >> 6;
        const int row16 = l & 15, kgrp = l >> 4;
        const int at = wv & 1, cq = wv >> 1;

        {
            const uint4* ph = (const uint4*)planes;
            const uint4* pl = (const uint4*)(planes + 32768);
            uint4* dh = (uint4*)Wh; uint4* dl = (uint4*)Wl;
#pragma unroll
            for (int i = 0; i < 8; ++i) {
                int g = i * 512 + tid;
                int c = g >> 4, ch = g & 15;
                int sw = c * 16 + (ch ^ (c & 15));
                dh[sw] = ph[g]; dl[sw] = pl[g];
            }
        }

        v8h rh[4], rl[4];
        {
            const float* rb = r + (size_t)(a0 + at * 16 + row16) * FR + kgrp * 8;
#pragma unroll
            for (int ks = 0; ks < 4; ++ks) {
                float4 x0 = *(const float4*)(rb + ks * 32);
                float4 x1 = *(const float4*)(rb + ks * 32 + 4);
                float xs[8] = {x0.x, x0.y, x0.z, x0.w, x1.x, x1.y, x1.z, x1.w};
#pragma unroll
                for (int j = 0; j < 8; ++j) {
                    _Float16 h = (_Float16)xs[j];
                    rh[ks][j] = h;
                    rl[ks][j] = (_Float16)((xs[j] - (float)h) * 4096.f);
                }
            }
        }
        __syncthreads();

        v4h hpack[4], lpack[4];
#pragma unroll
        for (int ct = 0; ct < 4; ++ct) {
            int crow = cq * 64 + ct * 16 + row16;
            v4f a = {0.f, 0.f, 0.f, 0.f}, cr = {0.f, 0.f, 0.f, 0.f};
            int rbo = crow * 128, sw = crow & 15;
#pragma unroll
            for (int ks = 0; ks < 4; ++ks) {
                int off = rbo + (((ks * 4 + kgrp) ^ sw) * 8);
                v8h wh = *(const v8h*)(Wh + off);
                v8h wl = *(const v8h*)(Wl + off);
                a  = __builtin_amdgcn_mfma_f32_16x16x32_f16(wh, rh[ks], a,  0, 0, 0);
                cr = __builtin_amdgcn_mfma_f32_16x16x32_f16(wh, rl[ks], cr, 0, 0, 0);
                cr = __builtin_amdgcn_mfma_f32_16x16x32_f16(wl, rh[ks], cr, 0, 0, 0);
            }
            int colb = cq * 64 + ct * 16 + kgrp * 4;
            const float* bp = (colb < 128) ? (b1s + colb) : (b1e + (colb - 128));
            float4 bv = *(const float4*)bp;
            float bvx[4] = {bv.x, bv.y, bv.z, bv.w};
#pragma unroll
            for (int j = 0; j < 4; ++j) {
                float v = fast_tanh(a[j] + cr[j] * 2.44140625e-4f + bvx[j]);
                _Float16 h = (_Float16)v;
                hpack[ct][j] = h;
                lpack[ct][j] = (_Float16)((v - (float)h) * 4096.f);
            }
        }
        __syncthreads();

        {
            int arow = at * 16 + row16;
#pragma unroll
            for (int ct = 0; ct < 4; ++ct) {
                int colb = cq * 64 + ct * 16 + kgrp * 4;
                int chs = (colb >> 3) ^ row16;
                int off = arow * 256 + chs * 8 + (colb & 7);
                *(v4h*)(h1h + off) = hpack[ct];
                *(v4h*)(h1l + off) = lpack[ct];
            }
            const uint4* ph = (const uint4*)(planes + 65536);
            const uint4* pl = (const uint4*)(planes + 81920);
            uint4* dh = (uint4*)W2h; uint4* dl = (uint4*)W2l;
#pragma unroll
            for (int i = 0; i < 4; ++i) {
                int g = i * 512 + tid;
                int c = g >> 4, ch = g & 15;
                int sw = c * 16 + (ch ^ (c & 15));
                dh[sw] = ph[g]; dl[sw] = pl[g];
            }
        }
        __syncthreads();

        {
            const int path = cq >> 1, half = cq & 1;
            const int arow = at * 16 + row16;
            v8h bh[4], bl[4];
#pragma unroll
            for (int ks = 0; ks < 4; ++ks) {
                int chunk = path * 16 + ks * 4 + kgrp;
                int off = arow * 256 + ((chunk ^ row16) * 8);
                bh[ks] = *(const v8h*)(h1h + off);
                bl[ks] = *(const v8h*)(h1l + off);
            }
            float ps = 0.f;
#pragma unroll
            for (int ct2 = 0; ct2 < 2; ++ct2) {
                int c2 = path * 64 + half * 32 + ct2 * 16 + row16;
                v4f a = {0.f, 0.f, 0.f, 0.f}, cr = {0.f, 0.f, 0.f, 0.f};
                int rbo = c2 * 128, sw = c2 & 15;
#pragma unroll
                for (int ks = 0; ks < 4; ++ks) {
                    int off = rbo + (((ks * 4 + kgrp) ^ sw) * 8);
                    v8h wh = *(const v8h*)(W2h + off);
                    v8h wl = *(const v8h*)(W2l + off);
                    a  = __builtin_amdgcn_mfma_f32_16x16x32_f16(wh, bh[ks], a,  0, 0, 0);
                    cr = __builtin_amdgcn_mfma_f32_16x16x32_f16(wh, bl[ks], cr, 0, 0, 0);
                    cr = __builtin_amdgcn_mfma_f32_16x16x32_f16(wl, bh[ks], cr, 0, 0, 0);
                }
                int cb = half * 32 + ct2 * 16 + kgrp * 4;
                float4 b2v = *(const float4*)((path ? b2e : b2s) + cb);
                float4 w3v = *(const float4*)((path ? w3e : w3s) + cb);
                float b2x[4] = {b2v.x, b2v.y, b2v.z, b2v.w};
                float w3x[4] = {w3v.x, w3v.y, w3v.z, w3v.w};
#pragma unroll
                for (int j = 0; j < 4; ++j) {
                    float h2 = fast_tanh(a[j] + cr[j] * 2.44140625e-4f + b2x[j]);
                    ps = fmaf(h2, w3x[j], ps);
                }
            }
            ps += __shfl_xor(ps, 16);
            ps += __shfl_xor(ps, 32);
            if (l < 16) mArr[cq * 32 + at * 16 + l] = ps;
        }
        __syncthreads();

        if (tid < 32) {
            int atom = a0 + tid;
            float ms = mArr[tid] + mArr[32 + tid] + b3s[0];
            float me = mArr[64 + tid] + mArr[96 + tid] + b3e[0];
            float sg = fmaf(10.f * ms, ms, 4.f);
            float p  = sg * sqrtf(sg);
            float q  = 0.31622776601683794f * fabsf(me);
            __half2 pq = __halves2half2(__float2half(p), __float2half(q));
            atomd[atom] = make_float4(xyz[3 * atom], xyz[3 * atom + 1],
                                      xyz[3 * atom + 2], __builtin_bit_cast(float, pq));
        }
    }
    grid.sync();

    // ---------------- phase R: pair energies ----------------
    {
        float4* atomdL = (float4*)ldsraw;                   // 128 KiB
        int*    off    = (int*)(ldsraw + 131072);           // 65 ints
        float*  bsum   = (float*)(ldsraw + 131072 + 272);   // 64 floats

#pragma unroll
        for (int i = 0; i < 16; ++i) atomdL[i * 512 + tid] = atomd[i * 512 + tid];
        if (tid < 64) {
            int run = num_pairs[tid];
#pragma unroll
            for (int d = 1; d < 64; d <<= 1) {
                int o = __shfl_up(run, d);
                if (tid >= d) run += o;
            }
            off[tid + 1] = run;
            if (tid == 0) off[0] = 0;
            bsum[tid] = 0.f;
        }
        __syncthreads();

        for (int pass = 0; pass < 2; ++pass) {
            const int base = ((bid * 512 + tid) * 2 + pass) * PPT;
            const bool fastall = __all(base + PPT <= P);
            if (fastall) {
                int pr2[PPT * 2];
                const int4* pp4 = (const int4*)(pairs + (size_t)base * 2);
#pragma unroll
                for (int i = 0; i < PPT / 2; ++i) {
                    int4 v = pp4[i];
                    pr2[4*i] = v.x; pr2[4*i+1] = v.y; pr2[4*i+2] = v.z; pr2[4*i+3] = v.w;
                }
                int s = 0;
#pragma unroll
                for (int st = 32; st; st >>= 1) { int ns = s + st; if (ns <= NSEG - 1 && off[ns] <= base) s = ns; }
                float acc = 0.f;
                if (base + PPT <= off[s + 1] || s == NSEG - 1) {
#pragma unroll
                    for (int i = 0; i < PPT; ++i)
                        acc += pair_e(atomdL, pr2[2 * i], pr2[2 * i + 1]);
                } else {
                    int off_next = off[s + 1];
#pragma unroll
                    for (int i = 0; i < PPT; ++i) {
                        int idx = base + i;
                        while (s < NSEG - 1 && idx >= off_next) {
                            if (acc != 0.f) atomicAdd(&bsum[s], acc);
                            acc = 0.f; ++s; off_next = off[s + 1];
                        }
                        acc += pair_e(atomdL, pr2[2 * i], pr2[2 * i + 1]);
                    }
                }
                int s0 = __builtin_amdgcn_readfirstlane(s);
                if (__all(s == s0)) {
                    float v = acc;
#pragma unroll
                    for (int o = 32; o; o >>= 1) v += __shfl_xor(v, o);
                    if ((tid & 63) == 0) atomicAdd(&bsum[s0], v);
                } else {
                    atomicAdd(&bsum[s], acc);
                }
            } else if (base < P) {
                int s = 0;
#pragma unroll
                for (int st = 32; st; st >>= 1) { int ns = s + st; if (ns <= NSEG - 1 && off[ns] <= base) s = ns; }
                int off_next = off[s + 1];
                float acc = 0.f;
                for (int i = 0; i < PPT; ++i) {
                    int idx = base + i;
                    if (idx >= P) break;
                    while (s < NSEG - 1 && idx >= off_next) {
                        if (acc != 0.f) atomicAdd(&bsum[s], acc);
                        acc = 0.f; ++s; off_next = off[s + 1];
                    }
                    acc += pair_e(atomdL, pairs[2 * (size_t)idx], pairs[2 * (size_t)idx + 1]);
                }
                if (acc != 0.f) atomicAdd(&bsum[s], acc);
            }
        }
        __syncthreads();
        if (tid < 64) blocksums[bid * 64 + tid] = bsum[tid];
    }
    grid.sync();

    // ---------------- phase F: deterministic final reduce (block 0) ----------------
    if (bid == 0) {
        float* red = (float*)ldsraw;   // [8][64]
        int b = tid & 63, part = tid >> 6;
        float s = 0.f;
        for (int j = part; j < 256; j += 8) s += blocksums[(size_t)j * 64 + b];
        red[part * 64 + b] = s;
        __syncthreads();
        if (tid < 64) {
            float t = 0.f;
#pragma unroll
            for (int p = 0; p < 8; ++p) t += red[p * 64 + tid];
            out[tid] = t;
        }
    }
}

// ================= fallback kernels (round-8 proven path) =================
__global__ __launch_bounds__(512) void k_prep(
    const float* __restrict__ w1s, const float* __restrict__ w1e,
    const float* __restrict__ w2s, const float* __restrict__ w2e,
    _Float16* __restrict__ planes)
{
    int i = blockIdx.x * 512 + threadIdx.x;
    if (i < 32768) {
        int c = i >> 7, k = i & 127;
        float x = (c < 128) ? w1s[k * 128 + c] : w1e[k * 128 + (c - 128)];
        _Float16 h = (_Float16)x;
        planes[i] = h;
        planes[32768 + i] = (_Float16)((x - (float)h) * 4096.f);
    } else if (i < 49152) {
        int u = i - 32768;
        int c = u >> 7, k = u & 127;
        float x = (c < 64) ? w2s[k * 64 + c] : w2e[k * 64 + (c - 64)];
        _Float16 h = (_Float16)x;
        planes[65536 + u] = h;
        planes[81920 + u] = (_Float16)((x - (float)h) * 4096.f);
    }
}

__global__ __launch_bounds__(512) void k_mm(
    const float* __restrict__ r, const float* __restrict__ xyz,
    const _Float16* __restrict__ planes,
    const float* __restrict__ b1s, const float* __restrict__ b1e,
    const float* __restrict__ b2s, const float* __restrict__ b2e,
    const float* __restrict__ w3s, const float* __restrict__ w3e,
    const float* __restrict__ b3s, const float* __restrict__ b3e,
    float4* __restrict__ atomd)
{
    extern __shared__ char ldsraw[];
    _Float16* Wh  = (_Float16*)ldsraw;
    _Float16* Wl  = Wh + 32768;
    _Float16* h1h = Wh;
    _Float16* h1l = Wh + 8192;
    _Float16* W2h = Wh + 16384;
    _Float16* W2l = Wh + 32768;
    float*    mArr = (float*)(ldsraw + 131072);

    const int tid = threadIdx.x;
    const int a0  = blockIdx.x * 32;
    const int l = tid & 63, wv = tid >> 6;
    const int row16 = l & 15, kgrp = l >> 4;
    const int at = wv & 1, cq = wv >> 1;

    {
        const uint4* ph = (const uint4*)planes;
        const uint4* pl = (const uint4*)(planes + 32768);
        uint4* dh = (uint4*)Wh; uint4* dl = (uint4*)Wl;
#pragma unroll
        for (int i = 0; i < 8; ++i) {
            int g = i * 512 + tid;
            int c = g >> 4, ch = g & 15;
            int sw = c * 16 + (ch ^ (c & 15));
            dh[sw] = ph[g]; dl[sw] = pl[g];
        }
    }
    v8h rh[4], rl[4];
    {
        const float* rb = r + (size_t)(a0 + at * 16 + row16) * FR + kgrp * 8;
#pragma unroll
        for (int ks = 0; ks < 4; ++ks) {
            float4 x0 = *(const float4*)(rb + ks * 32);
            float4 x1 = *(const float4*)(rb + ks * 32 + 4);
            float xs[8] = {x0.x, x0.y, x0.z, x0.w, x1.x, x1.y, x1.z, x1.w};
#pragma unroll
            for (int j = 0; j < 8; ++j) {
                _Float16 h = (_Float16)xs[j];
                rh[ks][j] = h;
                rl[ks][j] = (_Float16)((xs[j] - (float)h) * 4096.f);
            }
        }
    }
    __syncthreads();

    v4h hpack[4], lpack[4];
#pragma unroll
    for (int ct = 0; ct < 4; ++ct) {
        int crow = cq * 64 + ct * 16 + row16;
        v4f a = {0.f, 0.f, 0.f, 0.f}, cr = {0.f, 0.f, 0.f, 0.f};
        int rbo = crow * 128, sw = crow & 15;
#pragma unroll
        for (int ks = 0; ks < 4; ++ks) {
            int off = rbo + (((ks * 4 + kgrp) ^ sw) * 8);
            v8h wh = *(const v8h*)(Wh + off);
            v8h wl = *(const v8h*)(Wl + off);
            a  = __builtin_amdgcn_mfma_f32_16x16x32_f16(wh, rh[ks], a,  0, 0, 0);
            cr = __builtin_amdgcn_mfma_f32_16x16x32_f16(wh, rl[ks], cr, 0, 0, 0);
            cr = __builtin_amdgcn_mfma_f32_16x16x32_f16(wl, rh[ks], cr, 0, 0, 0);
        }
        int colb = cq * 64 + ct * 16 + kgrp * 4;
        const float* bp = (colb < 128) ? (b1s + colb) : (b1e + (colb - 128));
        float4 bv = *(const float4*)bp;
        float bvx[4] = {bv.x, bv.y, bv.z, bv.w};
#pragma unroll
        for (int j = 0; j < 4; ++j) {
            float v = fast_tanh(a[j] + cr[j] * 2.44140625e-4f + bvx[j]);
            _Float16 h = (_Float16)v;
            hpack[ct][j] = h;
            lpack[ct][j] = (_Float16)((v - (float)h) * 4096.f);
        }
    }
    __syncthreads();
    {
        int arow = at * 16 + row16;
#pragma unroll
        for (int ct = 0; ct < 4; ++ct) {
            int colb = cq * 64 + ct * 16 + kgrp * 4;
            int chs = (colb >> 3) ^ row16;
            int off = arow * 256 + chs * 8 + (colb & 7);
            *(v4h*)(h1h + off) = hpack[ct];
            *(v4h*)(h1l + off) = lpack[ct];
        }
        const uint4* ph = (const uint4*)(planes + 65536);
        const uint4* pl = (const uint4*)(planes + 81920);
        uint4* dh = (uint4*)W2h; uint4* dl = (uint4*)W2l;
#pragma unroll
        for (int i = 0; i < 4; ++i) {
            int g = i * 512 + tid;
            int c = g >> 4, ch = g & 15;
            int sw = c * 16 + (ch ^ (c & 15));
            dh[sw] = ph[g]; dl[sw] = pl[g];
        }
    }
    __syncthreads();
    {
        const int path = cq >> 1, half = cq & 1;
        const int arow = at * 16 + row16;
        v8h bh[4], bl[4];
#pragma unroll
        for (int ks = 0; ks < 4; ++ks) {
            int chunk = path * 16 + ks * 4 + kgrp;
            int off = arow * 256 + ((chunk ^ row16) * 8);
            bh[ks] = *(const v8h*)(h1h + off);
            bl[ks] = *(const v8h*)(h1l + off);
        }
        float ps = 0.f;
#pragma unroll
        for (int ct2 = 0; ct2 < 2; ++ct2) {
            int c2 = path * 64 + half * 32 + ct2 * 16 + row16;
            v4f a = {0.f, 0.f, 0.f, 0.f}, cr = {0.f, 0.f, 0.f, 0.f};
            int rbo = c2 * 128, sw = c2 & 15;
#pragma unroll
            for (int ks = 0; ks < 4; ++ks) {
                int off = rbo + (((ks * 4 + kgrp) ^ sw) * 8);
                v8h wh = *(const v8h*)(W2h + off);
                v8h wl = *(const v8h*)(W2l + off);
                a  = __builtin_amdgcn_mfma_f32_16x16x32_f16(wh, bh[ks], a,  0, 0, 0);
                cr = __builtin_amdgcn_mfma_f32_16x16x32_f16(wh, bl[ks], cr, 0, 0, 0);
                cr = __builtin_amdgcn_mfma_f32_16x16x32_f16(wl, bh[ks], cr, 0, 0, 0);
            }
            int cb = half * 32 + ct2 * 16 + kgrp * 4;
            float4 b2v = *(const float4*)((path ? b2e : b2s) + cb);
            float4 w3v = *(const float4*)((path ? w3e : w3s) + cb);
            float b2x[4] = {b2v.x, b2v.y, b2v.z, b2v.w};
            float w3x[4] = {w3v.x, w3v.y, w3v.z, w3v.w};
#pragma unroll
            for (int j = 0; j < 4; ++j) {
                float h2 = fast_tanh(a[j] + cr[j] * 2.44140625e-4f + b2x[j]);
                ps = fmaf(h2, w3x[j], ps);
            }
        }
        ps += __shfl_xor(ps, 16);
        ps += __shfl_xor(ps, 32);
        if (l < 16) mArr[cq * 32 + at * 16 + l] = ps;
    }
    __syncthreads();
    if (tid < 32) {
        int atom = a0 + tid;
        float ms = mArr[tid] + mArr[32 + tid] + b3s[0];
        float me = mArr[64 + tid] + mArr[96 + tid] + b3e[0];
        float sg = fmaf(10.f * ms, ms, 4.f);
        float p  = sg * sqrtf(sg);
        float q  = 0.31622776601683794f * fabsf(me);
        __half2 pq = __halves2half2(__float2half(p), __float2half(q));
        atomd[atom] = make_float4(xyz[3 * atom], xyz[3 * atom + 1],
                                  xyz[3 * atom + 2], __builtin_bit_cast(float, pq));
    }
}

__global__ __launch_bounds__(PT, 1) void k_pair(
    const float4* __restrict__ atomg, const int* __restrict__ pairs,
    const int* __restrict__ num_pairs,
    float* __restrict__ blocksums, int P)
{
    extern __shared__ char smem[];
    float4* atomd = (float4*)smem;
    int*    off   = (int*)(smem + NATOM * 16);
    float*  bsum  = (float*)(smem + NATOM * 16 + 68 * 4);

    const int tid = threadIdx.x;
    const int base = (blockIdx.x * PT + tid) * PPT;
    const bool fastall = __all(base + PPT <= P);

    int pr2[PPT * 2];
    if (fastall) {
        const int4* pp4 = (const int4*)(pairs + (size_t)base * 2);
#pragma unroll
        for (int i = 0; i < PPT / 2; ++i) {
            int4 v = pp4[i];
            pr2[4*i] = v.x; pr2[4*i+1] = v.y; pr2[4*i+2] = v.z; pr2[4*i+3] = v.w;
        }
    }
#pragma unroll
    for (int i = 0; i < NATOM / PT; ++i) atomd[i * PT + tid] = atomg[i * PT + tid];
    if (tid < 64) {
        int run = num_pairs[tid];
#pragma unroll
        for (int d = 1; d < 64; d <<= 1) {
            int o = __shfl_up(run, d);
            if (tid >= d) run += o;
        }
        off[tid + 1] = run;
        if (tid == 0) off[0] = 0;
        bsum[tid] = 0.f;
    }
    __syncthreads();

    if (fastall) {
        int s = 0;
#pragma unroll
        for (int st = 32; st; st >>= 1) { int ns = s + st; if (ns <= NSEG - 1 && off[ns] <= base) s = ns; }
        float acc = 0.f;
        if (base + PPT <= off[s + 1] || s == NSEG - 1) {
#pragma unroll
            for (int i = 0; i < PPT; ++i)
                acc += pair_e(atomd, pr2[2 * i], pr2[2 * i + 1]);
        } else {
            int off_next = off[s + 1];
#pragma unroll
            for (int i = 0; i < PPT; ++i) {
                int idx = base + i;
                while (s < NSEG - 1 && idx >= off_next) {
                    if (acc != 0.f) atomicAdd(&bsum[s], acc);
                    acc = 0.f; ++s; off_next = off[s + 1];
                }
                acc += pair_e(atomd, pr2[2 * i], pr2[2 * i + 1]);
            }
        }
        int s0 = __builtin_amdgcn_readfirstlane(s);
        if (__all(s == s0)) {
            float v = acc;
#pragma unroll
            for (int o = 32; o; o >>= 1) v += __shfl_xor(v, o);
            if ((tid & 63) == 0) atomicAdd(&bsum[s0], v);
        } else {
            atomicAdd(&bsum[s], acc);
        }
    } else if (base < P) {
        int s = 0;
#pragma unroll
        for (int st = 32; st; st >>= 1) { int ns = s + st; if (ns <= NSEG - 1 && off[ns] <= base) s = ns; }
        int off_next = off[s + 1];
        float acc = 0.f;
        for (int i = 0; i < PPT; ++i) {
            int idx = base + i;
            if (idx >= P) break;
            while (s < NSEG - 1 && idx >= off_next) {
                if (acc != 0.f) atomicAdd(&bsum[s], acc);
                acc = 0.f; ++s; off_next = off[s + 1];
            }
            acc += pair_e(atomd, pairs[2 * (size_t)idx], pairs[2 * (size_t)idx + 1]);
        }
        if (acc != 0.f) atomicAdd(&bsum[s], acc);
    }
    __syncthreads();
    if (tid < NSEG) blocksums[blockIdx.x * NSEG + tid] = bsum[tid];
}

__global__ __launch_bounds__(512) void k_reduce(const float* __restrict__ bs, float* __restrict__ out)
{
    __shared__ float red[8][NSEG];
    int b = threadIdx.x & 63, part = threadIdx.x >> 6;
    float s = 0.f;
    for (int j = part; j < PB; j += 8) s += bs[(size_t)j * NSEG + b];
    red[part][b] = s;
    __syncthreads();
    if (threadIdx.x < NSEG) {
        float t = 0.f;
#pragma unroll
        for (int p = 0; p < 8; ++p) t += red[p][threadIdx.x];
        out[threadIdx.x] = t;
    }
}

extern "C" void kernel_launch(void* const* d_in, const int* in_sizes, int n_in,
                              void* d_out, int out_size, void* d_ws, size_t ws_size,
                              hipStream_t stream)
{
    const float* r    = (const float*)d_in[0];
    const float* xyz  = (const float*)d_in[1];
    const int*   prs  = (const int*)d_in[2];
    const int*   np   = (const int*)d_in[3];
    const float* sW1  = (const float*)d_in[4];
    const float* sb1  = (const float*)d_in[5];
    const float* sW2  = (const float*)d_in[6];
    const float* sb2  = (const float*)d_in[7];
    const float* sW3  = (const float*)d_in[8];
    const float* sb3  = (const float*)d_in[9];
    const float* eW1  = (const float*)d_in[10];
    const float* eb1  = (const float*)d_in[11];
    const float* eW2  = (const float*)d_in[12];
    const float* eb2  = (const float*)d_in[13];
    const float* eW3  = (const float*)d_in[14];
    const float* eb3  = (const float*)d_in[15];
    float* out = (float*)d_out;
    int P = in_sizes[2] / 2;

    _Float16* planes = (_Float16*)d_ws;                          // 192 KB
    float4*   atomd  = (float4*)((char*)d_ws + 196608);          // 128 KB
    float*    bsums  = (float*)((char*)d_ws + 196608 + 131072);  // 64 KB

    size_t smem_all = 132096;
    hipFuncSetAttribute((const void*)k_all, hipFuncAttributeMaxDynamicSharedMemorySize, (int)smem_all);

    void* args[] = { (void*)&r, (void*)&xyz, (void*)&prs, (void*)&np,
                     (void*)&sW1, (void*)&sb1, (void*)&sW2, (void*)&sb2,
                     (void*)&sW3, (void*)&sb3, (void*)&eW1, (void*)&eb1,
                     (void*)&eW2, (void*)&eb2, (void*)&eW3, (void*)&eb3,
                     (void*)&planes, (void*)&atomd, (void*)&bsums,
                     (void*)&out, (void*)&P };
    hipError_t e = hipLaunchCooperativeKernel((const void*)k_all, dim3(256), dim3(512),
                                              args, (unsigned)smem_all, stream);
    if (e != hipSuccess) {
        (void)hipGetLastError();   // clear; fall back to 4-kernel path
        k_prep<<<96, 512, 0, stream>>>(sW1, eW1, sW2, eW2, planes);
        size_t smem1 = 131072 + 512;
        hipFuncSetAttribute((const void*)k_mm, hipFuncAttributeMaxDynamicSharedMemorySize, (int)smem1);
        k_mm<<<NATOM / 32, 512, smem1, stream>>>(r, xyz, planes, sb1, eb1, sb2, eb2,
                                                 sW3, eW3, sb3, eb3, atomd);
        size_t smem = (size_t)NATOM * 16 + 68 * 4 + NSEG * 4;
        hipFuncSetAttribute((const void*)k_pair, hipFuncAttributeMaxDynamicSharedMemorySize, (int)smem);
        k_pair<<<PB, PT, smem, stream>>>(atomd, prs, np, bsums, P);
        k_reduce<<<1, 512, 0, stream>>>(bsums, out);
    }
}

// Round 11
// 34.791 us; speedup vs baseline: 3.4418x; 3.4418x over previous
//
#include <hip/hip_runtime.h>
#include <hip/hip_fp16.h>

#define NATOM 8192
#define FR    128
#define NSEG  64
#define PB    256     // pair-kernel blocks
#define PT    1024    // pair-kernel threads/block
#define PPT   16      // pairs per thread

typedef _Float16 v8h __attribute__((ext_vector_type(8)));
typedef _Float16 v4h __attribute__((ext_vector_type(4)));
typedef float    v4f __attribute__((ext_vector_type(4)));

__device__ __forceinline__ float fast_tanh(float x)
{
    float t = __expf(2.f * x);
    return 1.f - 2.f * __builtin_amdgcn_rcpf(t + 1.f);
}

// ---------------- kernel 1: fused weight-split + MFMA MLP ----------------
// Round-8 verified body (128 blocks x 512 thr, 64 atoms/block, at=wv&3,
// chf=wv>>2). Only change: W staging reads the ORIGINAL f32 weights and does
// the hi/lo f16 split inline (replaces k_prep + planes round-trip; same bytes).
// Chunk remap (c = g&255, ch = g>>8) keeps global reads 256B-coalesced per wave.
__global__ __launch_bounds__(512) void k_mm(
    const float* __restrict__ r, const float* __restrict__ xyz,
    const float* __restrict__ w1s, const float* __restrict__ b1s,
    const float* __restrict__ w2s, const float* __restrict__ b2s,
    const float* __restrict__ w3s, const float* __restrict__ b3s,
    const float* __restrict__ w1e, const float* __restrict__ b1e,
    const float* __restrict__ w2e, const float* __restrict__ b2e,
    const float* __restrict__ w3e, const float* __restrict__ b3e,
    float4* __restrict__ atomd)
{
    extern __shared__ char ldsraw[];
    _Float16* Wh  = (_Float16*)ldsraw;           // phase1: [256 c][128 k] swizzled
    _Float16* Wl  = Wh + 32768;
    _Float16* h1h = Wh;                          // phase2: [64 a][256 c] swizzled
    _Float16* h1l = Wh + 16384;
    _Float16* W2h = Wh + 32768;                  // [128 c][128 k] swizzled
    _Float16* W2l = Wh + 49152;
    float*    mArr = (float*)(ldsraw + 131072);  // [128]

    const int tid = threadIdx.x;
    const int a0  = blockIdx.x * 64;
    const int l = tid & 63, wv = tid >> 6;
    const int row16 = l & 15, kgrp = l >> 4;
    const int at = wv & 3, chf = wv >> 2;

    // ---- W1 inline split+transpose staging (f32 -> hi/lo f16, swizzled) ----
#pragma unroll
    for (int i = 0; i < 8; ++i) {
        int g = i * 512 + tid;           // [0,4096) chunk id
        int c = g & 255, ch = g >> 8;    // col (sigma||eps), k-chunk
        const float* wp = (c < 128) ? (w1s + c) : (w1e + (c - 128));
        v8h hh, ll;
#pragma unroll
        for (int j = 0; j < 8; ++j) {
            float x = wp[(ch * 8 + j) * 128];   // 256B coalesced across lanes
            _Float16 h = (_Float16)x;
            hh[j] = h;
            ll[j] = (_Float16)((x - (float)h) * 4096.f);
        }
        int sw = c * 16 + (ch ^ (c & 15));
        *(v8h*)(Wh + sw * 8) = hh;
        *(v8h*)(Wl + sw * 8) = ll;
    }

    // ---- r fragments (global, inline hi/lo split), k = ks*32 + kgrp*8 + j ----
    v8h rh[4], rl[4];
    {
        const float* rb = r + (size_t)(a0 + at * 16 + row16) * FR + kgrp * 8;
#pragma unroll
        for (int ks = 0; ks < 4; ++ks) {
            float4 x0 = *(const float4*)(rb + ks * 32);
            float4 x1 = *(const float4*)(rb + ks * 32 + 4);
            float xs[8] = {x0.x, x0.y, x0.z, x0.w, x1.x, x1.y, x1.z, x1.w};
#pragma unroll
            for (int j = 0; j < 8; ++j) {
                _Float16 h = (_Float16)xs[j];
                rh[ks][j] = h;
                rl[ks][j] = (_Float16)((xs[j] - (float)h) * 4096.f);
            }
        }
    }
    __syncthreads();

    // ---- GEMM1: wave covers cols [chf*128,+128), atoms [at*16,+16) ----
    v4h hpack[8], lpack[8];
#pragma unroll
    for (int ct = 0; ct < 8; ++ct) {
        int crow = chf * 128 + ct * 16 + row16;
        v4f a = {0.f, 0.f, 0.f, 0.f}, cr = {0.f, 0.f, 0.f, 0.f};
        int rbo = crow * 128, sw = crow & 15;
#pragma unroll
        for (int ks = 0; ks < 4; ++ks) {
            int off = rbo + (((ks * 4 + kgrp) ^ sw) * 8);
            v8h wh = *(const v8h*)(Wh + off);
            v8h wl = *(const v8h*)(Wl + off);
            a  = __builtin_amdgcn_mfma_f32_16x16x32_f16(wh, rh[ks], a,  0, 0, 0);
            cr = __builtin_amdgcn_mfma_f32_16x16x32_f16(wh, rl[ks], cr, 0, 0, 0);
            cr = __builtin_amdgcn_mfma_f32_16x16x32_f16(wl, rh[ks], cr, 0, 0, 0);
        }
        int colb = chf * 128 + ct * 16 + kgrp * 4;
        const float* bp = (colb < 128) ? (b1s + colb) : (b1e + (colb - 128));
        float4 bv = *(const float4*)bp;
        float bvx[4] = {bv.x, bv.y, bv.z, bv.w};
#pragma unroll
        for (int j = 0; j < 4; ++j) {
            float v = fast_tanh(a[j] + cr[j] * 2.44140625e-4f + bvx[j]);
            _Float16 h = (_Float16)v;
            hpack[ct][j] = h;
            lpack[ct][j] = (_Float16)((v - (float)h) * 4096.f);
        }
    }
    __syncthreads();   // all W1 reads done; LDS reused below

    // ---- write h1 (swizzled) + W2 inline split staging ----
    {
        int arow = at * 16 + row16;
#pragma unroll
        for (int ct = 0; ct < 8; ++ct) {
            int colb = chf * 128 + ct * 16 + kgrp * 4;
            int chs = (colb >> 3) ^ row16;
            int off = arow * 256 + chs * 8 + (colb & 7);
            *(v4h*)(h1h + off) = hpack[ct];
            *(v4h*)(h1l + off) = lpack[ct];
        }
#pragma unroll
        for (int i = 0; i < 4; ++i) {
            int g = i * 512 + tid;           // [0,2048)
            int c = g & 127, ch = g >> 7;
            const float* wp = (c < 64) ? (w2s + c) : (w2e + (c - 64));
            v8h hh, ll;
#pragma unroll
            for (int j = 0; j < 8; ++j) {
                float x = wp[(ch * 8 + j) * 64];   // 256B coalesced across lanes
                _Float16 h = (_Float16)x;
                hh[j] = h;
                ll[j] = (_Float16)((x - (float)h) * 4096.f);
            }
            int sw = c * 16 + (ch ^ (c & 15));
            *(v8h*)(W2h + sw * 8) = hh;
            *(v8h*)(W2l + sw * 8) = ll;
        }
    }
    __syncthreads();

    // ---- GEMM2 (path = chf) + layer 3 ----
    {
        const int arow = at * 16 + row16;
        v8h bh[4], bl[4];
#pragma unroll
        for (int ks = 0; ks < 4; ++ks) {
            int chunk = chf * 16 + ks * 4 + kgrp;
            int off = arow * 256 + ((chunk ^ row16) * 8);
            bh[ks] = *(const v8h*)(h1h + off);
            bl[ks] = *(const v8h*)(h1l + off);
        }
        float ps = 0.f;
#pragma unroll
        for (int ct2 = 0; ct2 < 4; ++ct2) {
            int c2 = chf * 64 + ct2 * 16 + row16;
            v4f a = {0.f, 0.f, 0.f, 0.f}, cr = {0.f, 0.f, 0.f, 0.f};
            int rbo = c2 * 128, sw = c2 & 15;
#pragma unroll
            for (int ks = 0; ks < 4; ++ks) {
                int off = rbo + (((ks * 4 + kgrp) ^ sw) * 8);
                v8h wh = *(const v8h*)(W2h + off);
                v8h wl = *(const v8h*)(W2l + off);
                a  = __builtin_amdgcn_mfma_f32_16x16x32_f16(wh, bh[ks], a,  0, 0, 0);
                cr = __builtin_amdgcn_mfma_f32_16x16x32_f16(wh, bl[ks], cr, 0, 0, 0);
                cr = __builtin_amdgcn_mfma_f32_16x16x32_f16(wl, bh[ks], cr, 0, 0, 0);
            }
            int cb = ct2 * 16 + kgrp * 4;
            float4 b2v = *(const float4*)((chf ? b2e : b2s) + cb);
            float4 w3v = *(const float4*)((chf ? w3e : w3s) + cb);
            float b2x[4] = {b2v.x, b2v.y, b2v.z, b2v.w};
            float w3x[4] = {w3v.x, w3v.y, w3v.z, w3v.w};
#pragma unroll
            for (int j = 0; j < 4; ++j) {
                float h2 = fast_tanh(a[j] + cr[j] * 2.44140625e-4f + b2x[j]);
                ps = fmaf(h2, w3x[j], ps);
            }
        }
        ps += __shfl_xor(ps, 16);
        ps += __shfl_xor(ps, 32);
        if (l < 16) mArr[chf * 64 + at * 16 + l] = ps + (chf ? b3e[0] : b3s[0]);
    }
    __syncthreads();

    if (tid < 64) {
        int atom = a0 + tid;
        float ms = mArr[tid], me = mArr[64 + tid];
        float sg = fmaf(10.f * ms, ms, 4.f);            // sigma = 4 + 10 m^2
        float p  = sg * sqrtf(sg);                      // sigma^1.5
        float q  = 0.31622776601683794f * fabsf(me);    // sqrt(eps)
        __half2 pq = __halves2half2(__float2half(p), __float2half(q));
        atomd[atom] = make_float4(xyz[3 * atom], xyz[3 * atom + 1],
                                  xyz[3 * atom + 2], __builtin_bit_cast(float, pq));
    }
}

// ---------------- kernel 2: pair energies + direct atomic output ----------------
__device__ __forceinline__ float pair_e(const float4* atomd, int ia, int ib)
{
    float4 A = atomd[ia], B = atomd[ib];
    float dx = A.x - B.x, dy = A.y - B.y, dz = A.z - B.z;
    float D2 = fmaf(dx, dx, fmaf(dy, dy, dz * dz));
    float inv = __builtin_amdgcn_rcpf(D2);
    float inv3 = inv * inv * inv;
    __half2 ha = __builtin_bit_cast(__half2, A.w);
    __half2 hb = __builtin_bit_cast(__half2, B.w);
    float pp = __low2float(ha) * __low2float(hb);    // (sig_i*sig_j)^1.5
    float qq = __high2float(ha) * __high2float(hb);  // eps_mixed
    float s6 = pp * pp * inv3;                       // (sig_i*sig_j)^3 / D2^3
    return 4.f * qq * (s6 * s6 - s6);
}

__global__ __launch_bounds__(PT, 1) void k_pair(
    const float4* __restrict__ atomg, const int* __restrict__ pairs,
    const int* __restrict__ num_pairs,
    float* __restrict__ out, int P)
{
    extern __shared__ char smem[];
    float4* atomd = (float4*)smem;                         // 8192 * 16B = 128 KiB
    int*    off   = (int*)(smem + NATOM * 16);             // 65 ints (+pad)
    float*  bsum  = (float*)(smem + NATOM * 16 + 68 * 4);  // 64 floats

    const int tid = threadIdx.x;

#pragma unroll
    for (int i = 0; i < NATOM / PT; ++i) atomd[i * PT + tid] = atomg[i * PT + tid];
    if (tid < 64) {
        int run = num_pairs[tid];
#pragma unroll
        for (int d = 1; d < 64; d <<= 1) {
            int o = __shfl_up(run, d);
            if (tid >= d) run += o;
        }
        off[tid + 1] = run;
        if (tid == 0) off[0] = 0;
        bsum[tid] = 0.f;
    }
    __syncthreads();

    const int base = (blockIdx.x * PT + tid) * PPT;
    const bool fast = (base + PPT <= P);

    if (__all(fast)) {
        int pr2[PPT * 2];
        const int4* pp4 = (const int4*)(pairs + (size_t)base * 2);
#pragma unroll
        for (int i = 0; i < PPT / 2; ++i) {
            int4 v = pp4[i];
            pr2[4*i] = v.x; pr2[4*i+1] = v.y; pr2[4*i+2] = v.z; pr2[4*i+3] = v.w;
        }
        int s = 0;
#pragma unroll
        for (int st = 32; st; st >>= 1) { int ns = s + st; if (ns <= NSEG - 1 && off[ns] <= base) s = ns; }
        float acc = 0.f;
        if (base + PPT <= off[s + 1] || s == NSEG - 1) {
#pragma unroll
            for (int i = 0; i < PPT; ++i)
                acc += pair_e(atomd, pr2[2 * i], pr2[2 * i + 1]);
        } else {
            int off_next = off[s + 1];
#pragma unroll
            for (int i = 0; i < PPT; ++i) {
                int idx = base + i;
                while (s < NSEG - 1 && idx >= off_next) {
                    if (acc != 0.f) atomicAdd(&bsum[s], acc);
                    acc = 0.f; ++s; off_next = off[s + 1];
                }
                acc += pair_e(atomd, pr2[2 * i], pr2[2 * i + 1]);
            }
        }
        int s0 = __builtin_amdgcn_readfirstlane(s);
        if (__all(s == s0)) {
            float v = acc;
#pragma unroll
            for (int o = 32; o; o >>= 1) v += __shfl_xor(v, o);
            if ((tid & 63) == 0) atomicAdd(&bsum[s0], v);
        } else {
            atomicAdd(&bsum[s], acc);
        }
    } else if (base < P) {
        int s = 0;
#pragma unroll
        for (int st = 32; st; st >>= 1) { int ns = s + st; if (ns <= NSEG - 1 && off[ns] <= base) s = ns; }
        int off_next = off[s + 1];
        float acc = 0.f;
        for (int i = 0; i < PPT; ++i) {
            int idx = base + i;
            if (idx >= P) break;
            while (s < NSEG - 1 && idx >= off_next) {
                if (acc != 0.f) atomicAdd(&bsum[s], acc);
                acc = 0.f; ++s; off_next = off[s + 1];
            }
            acc += pair_e(atomd, pairs[2 * (size_t)idx], pairs[2 * (size_t)idx + 1]);
        }
        if (acc != 0.f) atomicAdd(&bsum[s], acc);
    }
    __syncthreads();
    // direct device-scope atomic accumulation into d_out (zeroed via memsetAsync);
    // 256 blocks x 64 addresses, ulp-level ordering noise vs 8.8e16 threshold
    if (tid < NSEG) atomicAdd(&out[tid], bsum[tid]);
}

extern "C" void kernel_launch(void* const* d_in, const int* in_sizes, int n_in,
                              void* d_out, int out_size, void* d_ws, size_t ws_size,
                              hipStream_t stream)
{
    const float* r    = (const float*)d_in[0];
    const float* xyz  = (const float*)d_in[1];
    const int*   prs  = (const int*)d_in[2];
    const int*   np   = (const int*)d_in[3];
    const float* sW1  = (const float*)d_in[4];
    const float* sb1  = (const float*)d_in[5];
    const float* sW2  = (const float*)d_in[6];
    const float* sb2  = (const float*)d_in[7];
    const float* sW3  = (const float*)d_in[8];
    const float* sb3  = (const float*)d_in[9];
    const float* eW1  = (const float*)d_in[10];
    const float* eb1  = (const float*)d_in[11];
    const float* eW2  = (const float*)d_in[12];
    const float* eb2  = (const float*)d_in[13];
    const float* eW3  = (const float*)d_in[14];
    const float* eb3  = (const float*)d_in[15];
    float* out = (float*)d_out;
    const int P = in_sizes[2] / 2;

    float4* atomd = (float4*)d_ws;               // 8192 float4 = 128 KB

    hipMemsetAsync(out, 0, (size_t)out_size * sizeof(float), stream);

    size_t smem1 = 131072 + 512;
    hipFuncSetAttribute((const void*)k_mm, hipFuncAttributeMaxDynamicSharedMemorySize, (int)smem1);
    k_mm<<<NATOM / 64, 512, smem1, stream>>>(r, xyz, sW1, sb1, sW2, sb2, sW3, sb3,
                                             eW1, eb1, eW2, eb2, eW3, eb3, atomd);

    size_t smem = (size_t)NATOM * 16 + 68 * 4 + NSEG * 4;   // 131,600 B
    hipFuncSetAttribute((const void*)k_pair, hipFuncAttributeMaxDynamicSharedMemorySize, (int)smem);
    k_pair<<<PB, PT, smem, stream>>>(atomd, prs, np, out, P);
}

// Round 12
// 33.712 us; speedup vs baseline: 3.5521x; 1.0320x over previous
//
#include <hip/hip_runtime.h>
#include <hip/hip_fp16.h>

#define NATOM 8192
#define FR    128
#define NSEG  64
#define PB    256     // pair-kernel blocks
#define PT    1024    // pair-kernel threads/block
#define PPT   16      // pairs per thread

typedef _Float16 v8h __attribute__((ext_vector_type(8)));
typedef _Float16 v4h __attribute__((ext_vector_type(4)));
typedef float    v4f __attribute__((ext_vector_type(4)));

__device__ __forceinline__ float fast_tanh(float x)
{
    float t = __expf(2.f * x);
    return 1.f - 2.f * __builtin_amdgcn_rcpf(t + 1.f);
}

// ---------------- kernel 1: fused weight-split + MFMA MLP ----------------
// Round-11 verified body (128 blocks x 512 thr, 64 atoms/block). Only change:
// block 0 zeroes d_out (replaces the hipMemsetAsync dispatch; stream-ordered
// before k_pair's atomics, re-done every call -> deterministic).
__global__ __launch_bounds__(512) void k_mm(
    const float* __restrict__ r, const float* __restrict__ xyz,
    const float* __restrict__ w1s, const float* __restrict__ b1s,
    const float* __restrict__ w2s, const float* __restrict__ b2s,
    const float* __restrict__ w3s, const float* __restrict__ b3s,
    const float* __restrict__ w1e, const float* __restrict__ b1e,
    const float* __restrict__ w2e, const float* __restrict__ b2e,
    const float* __restrict__ w3e, const float* __restrict__ b3e,
    float4* __restrict__ atomd, float* __restrict__ out)
{
    extern __shared__ char ldsraw[];
    _Float16* Wh  = (_Float16*)ldsraw;           // phase1: [256 c][128 k] swizzled
    _Float16* Wl  = Wh + 32768;
    _Float16* h1h = Wh;                          // phase2: [64 a][256 c] swizzled
    _Float16* h1l = Wh + 16384;
    _Float16* W2h = Wh + 32768;                  // [128 c][128 k] swizzled
    _Float16* W2l = Wh + 49152;
    float*    mArr = (float*)(ldsraw + 131072);  // [128]

    const int tid = threadIdx.x;
    const int a0  = blockIdx.x * 64;
    const int l = tid & 63, wv = tid >> 6;
    const int row16 = l & 15, kgrp = l >> 4;
    const int at = wv & 3, chf = wv >> 2;

    if (blockIdx.x == 0 && tid < NSEG) out[tid] = 0.f;   // replaces memset dispatch

    // ---- W1 inline split+transpose staging (f32 -> hi/lo f16, swizzled) ----
#pragma unroll
    for (int i = 0; i < 8; ++i) {
        int g = i * 512 + tid;           // [0,4096) chunk id
        int c = g & 255, ch = g >> 8;    // col (sigma||eps), k-chunk
        const float* wp = (c < 128) ? (w1s + c) : (w1e + (c - 128));
        v8h hh, ll;
#pragma unroll
        for (int j = 0; j < 8; ++j) {
            float x = wp[(ch * 8 + j) * 128];   // 256B coalesced across lanes
            _Float16 h = (_Float16)x;
            hh[j] = h;
            ll[j] = (_Float16)((x - (float)h) * 4096.f);
        }
        int sw = c * 16 + (ch ^ (c & 15));
        *(v8h*)(Wh + sw * 8) = hh;
        *(v8h*)(Wl + sw * 8) = ll;
    }

    // ---- r fragments (global, inline hi/lo split), k = ks*32 + kgrp*8 + j ----
    v8h rh[4], rl[4];
    {
        const float* rb = r + (size_t)(a0 + at * 16 + row16) * FR + kgrp * 8;
#pragma unroll
        for (int ks = 0; ks < 4; ++ks) {
            float4 x0 = *(const float4*)(rb + ks * 32);
            float4 x1 = *(const float4*)(rb + ks * 32 + 4);
            float xs[8] = {x0.x, x0.y, x0.z, x0.w, x1.x, x1.y, x1.z, x1.w};
#pragma unroll
            for (int j = 0; j < 8; ++j) {
                _Float16 h = (_Float16)xs[j];
                rh[ks][j] = h;
                rl[ks][j] = (_Float16)((xs[j] - (float)h) * 4096.f);
            }
        }
    }
    __syncthreads();

    // ---- GEMM1: wave covers cols [chf*128,+128), atoms [at*16,+16) ----
    v4h hpack[8], lpack[8];
#pragma unroll
    for (int ct = 0; ct < 8; ++ct) {
        int crow = chf * 128 + ct * 16 + row16;
        v4f a = {0.f, 0.f, 0.f, 0.f}, cr = {0.f, 0.f, 0.f, 0.f};
        int rbo = crow * 128, sw = crow & 15;
#pragma unroll
        for (int ks = 0; ks < 4; ++ks) {
            int off = rbo + (((ks * 4 + kgrp) ^ sw) * 8);
            v8h wh = *(const v8h*)(Wh + off);
            v8h wl = *(const v8h*)(Wl + off);
            a  = __builtin_amdgcn_mfma_f32_16x16x32_f16(wh, rh[ks], a,  0, 0, 0);
            cr = __builtin_amdgcn_mfma_f32_16x16x32_f16(wh, rl[ks], cr, 0, 0, 0);
            cr = __builtin_amdgcn_mfma_f32_16x16x32_f16(wl, rh[ks], cr, 0, 0, 0);
        }
        int colb = chf * 128 + ct * 16 + kgrp * 4;
        const float* bp = (colb < 128) ? (b1s + colb) : (b1e + (colb - 128));
        float4 bv = *(const float4*)bp;
        float bvx[4] = {bv.x, bv.y, bv.z, bv.w};
#pragma unroll
        for (int j = 0; j < 4; ++j) {
            float v = fast_tanh(a[j] + cr[j] * 2.44140625e-4f + bvx[j]);
            _Float16 h = (_Float16)v;
            hpack[ct][j] = h;
            lpack[ct][j] = (_Float16)((v - (float)h) * 4096.f);
        }
    }
    __syncthreads();   // all W1 reads done; LDS reused below

    // ---- write h1 (swizzled) + W2 inline split staging ----
    {
        int arow = at * 16 + row16;
#pragma unroll
        for (int ct = 0; ct < 8; ++ct) {
            int colb = chf * 128 + ct * 16 + kgrp * 4;
            int chs = (colb >> 3) ^ row16;
            int off = arow * 256 + chs * 8 + (colb & 7);
            *(v4h*)(h1h + off) = hpack[ct];
            *(v4h*)(h1l + off) = lpack[ct];
        }
#pragma unroll
        for (int i = 0; i < 4; ++i) {
            int g = i * 512 + tid;           // [0,2048)
            int c = g & 127, ch = g >> 7;
            const float* wp = (c < 64) ? (w2s + c) : (w2e + (c - 64));
            v8h hh, ll;
#pragma unroll
            for (int j = 0; j < 8; ++j) {
                float x = wp[(ch * 8 + j) * 64];   // 256B coalesced across lanes
                _Float16 h = (_Float16)x;
                hh[j] = h;
                ll[j] = (_Float16)((x - (float)h) * 4096.f);
            }
            int sw = c * 16 + (ch ^ (c & 15));
            *(v8h*)(W2h + sw * 8) = hh;
            *(v8h*)(W2l + sw * 8) = ll;
        }
    }
    __syncthreads();

    // ---- GEMM2 (path = chf) + layer 3 ----
    {
        const int arow = at * 16 + row16;
        v8h bh[4], bl[4];
#pragma unroll
        for (int ks = 0; ks < 4; ++ks) {
            int chunk = chf * 16 + ks * 4 + kgrp;
            int off = arow * 256 + ((chunk ^ row16) * 8);
            bh[ks] = *(const v8h*)(h1h + off);
            bl[ks] = *(const v8h*)(h1l + off);
        }
        float ps = 0.f;
#pragma unroll
        for (int ct2 = 0; ct2 < 4; ++ct2) {
            int c2 = chf * 64 + ct2 * 16 + row16;
            v4f a = {0.f, 0.f, 0.f, 0.f}, cr = {0.f, 0.f, 0.f, 0.f};
            int rbo = c2 * 128, sw = c2 & 15;
#pragma unroll
            for (int ks = 0; ks < 4; ++ks) {
                int off = rbo + (((ks * 4 + kgrp) ^ sw) * 8);
                v8h wh = *(const v8h*)(W2h + off);
                v8h wl = *(const v8h*)(W2l + off);
                a  = __builtin_amdgcn_mfma_f32_16x16x32_f16(wh, bh[ks], a,  0, 0, 0);
                cr = __builtin_amdgcn_mfma_f32_16x16x32_f16(wh, bl[ks], cr, 0, 0, 0);
                cr = __builtin_amdgcn_mfma_f32_16x16x32_f16(wl, bh[ks], cr, 0, 0, 0);
            }
            int cb = ct2 * 16 + kgrp * 4;
            float4 b2v = *(const float4*)((chf ? b2e : b2s) + cb);
            float4 w3v = *(const float4*)((chf ? w3e : w3s) + cb);
            float b2x[4] = {b2v.x, b2v.y, b2v.z, b2v.w};
            float w3x[4] = {w3v.x, w3v.y, w3v.z, w3v.w};
#pragma unroll
            for (int j = 0; j < 4; ++j) {
                float h2 = fast_tanh(a[j] + cr[j] * 2.44140625e-4f + b2x[j]);
                ps = fmaf(h2, w3x[j], ps);
            }
        }
        ps += __shfl_xor(ps, 16);
        ps += __shfl_xor(ps, 32);
        if (l < 16) mArr[chf * 64 + at * 16 + l] = ps + (chf ? b3e[0] : b3s[0]);
    }
    __syncthreads();

    if (tid < 64) {
        int atom = a0 + tid;
        float ms = mArr[tid], me = mArr[64 + tid];
        float sg = fmaf(10.f * ms, ms, 4.f);            // sigma = 4 + 10 m^2
        float p  = sg * sqrtf(sg);                      // sigma^1.5
        float q  = 0.31622776601683794f * fabsf(me);    // sqrt(eps)
        __half2 pq = __halves2half2(__float2half(p), __float2half(q));
        atomd[atom] = make_float4(xyz[3 * atom], xyz[3 * atom + 1],
                                  xyz[3 * atom + 2], __builtin_bit_cast(float, pq));
    }
}

// ---------------- kernel 2: pair energies + direct atomic output ----------------
__device__ __forceinline__ float pair_e(const float4* atomd, int ia, int ib)
{
    float4 A = atomd[ia], B = atomd[ib];
    float dx = A.x - B.x, dy = A.y - B.y, dz = A.z - B.z;
    float D2 = fmaf(dx, dx, fmaf(dy, dy, dz * dz));
    float inv = __builtin_amdgcn_rcpf(D2);
    float inv3 = inv * inv * inv;
    __half2 ha = __builtin_bit_cast(__half2, A.w);
    __half2 hb = __builtin_bit_cast(__half2, B.w);
    float pp = __low2float(ha) * __low2float(hb);    // (sig_i*sig_j)^1.5
    float qq = __high2float(ha) * __high2float(hb);  // eps_mixed
    float s6 = pp * pp * inv3;                       // (sig_i*sig_j)^3 / D2^3
    return 4.f * qq * (s6 * s6 - s6);
}

__global__ __launch_bounds__(PT, 1) void k_pair(
    const float4* __restrict__ atomg, const int* __restrict__ pairs,
    const int* __restrict__ num_pairs,
    float* __restrict__ out, int P)
{
    extern __shared__ char smem[];
    float4* atomd = (float4*)smem;                         // 8192 * 16B = 128 KiB
    int*    off   = (int*)(smem + NATOM * 16);             // 65 ints (+pad)
    float*  bsum  = (float*)(smem + NATOM * 16 + 68 * 4);  // 64 floats

    const int tid = threadIdx.x;
    const int base = (blockIdx.x * PT + tid) * PPT;
    const bool fastall = __all(base + PPT <= P);

    // pairs prefetch FIRST: 128B/thread HBM stream overlaps the LDS staging
    int pr2[PPT * 2];
    if (fastall) {
        const int4* pp4 = (const int4*)(pairs + (size_t)base * 2);
#pragma unroll
        for (int i = 0; i < PPT / 2; ++i) {
            int4 v = pp4[i];
            pr2[4*i] = v.x; pr2[4*i+1] = v.y; pr2[4*i+2] = v.z; pr2[4*i+3] = v.w;
        }
    }

#pragma unroll
    for (int i = 0; i < NATOM / PT; ++i) atomd[i * PT + tid] = atomg[i * PT + tid];
    if (tid < 64) {
        int run = num_pairs[tid];
#pragma unroll
        for (int d = 1; d < 64; d <<= 1) {
            int o = __shfl_up(run, d);
            if (tid >= d) run += o;
        }
        off[tid + 1] = run;
        if (tid == 0) off[0] = 0;
        bsum[tid] = 0.f;
    }
    __syncthreads();

    if (fastall) {
        int s = 0;
#pragma unroll
        for (int st = 32; st; st >>= 1) { int ns = s + st; if (ns <= NSEG - 1 && off[ns] <= base) s = ns; }
        float acc = 0.f;
        if (base + PPT <= off[s + 1] || s == NSEG - 1) {
#pragma unroll
            for (int i = 0; i < PPT; ++i)
                acc += pair_e(atomd, pr2[2 * i], pr2[2 * i + 1]);
        } else {
            int off_next = off[s + 1];
#pragma unroll
            for (int i = 0; i < PPT; ++i) {
                int idx = base + i;
                while (s < NSEG - 1 && idx >= off_next) {
                    if (acc != 0.f) atomicAdd(&bsum[s], acc);
                    acc = 0.f; ++s; off_next = off[s + 1];
                }
                acc += pair_e(atomd, pr2[2 * i], pr2[2 * i + 1]);
            }
        }
        int s0 = __builtin_amdgcn_readfirstlane(s);
        if (__all(s == s0)) {
            float v = acc;
#pragma unroll
            for (int o = 32; o; o >>= 1) v += __shfl_xor(v, o);
            if ((tid & 63) == 0) atomicAdd(&bsum[s0], v);
        } else {
            atomicAdd(&bsum[s], acc);
        }
    } else if (base < P) {
        int s = 0;
#pragma unroll
        for (int st = 32; st; st >>= 1) { int ns = s + st; if (ns <= NSEG - 1 && off[ns] <= base) s = ns; }
        int off_next = off[s + 1];
        float acc = 0.f;
        for (int i = 0; i < PPT; ++i) {
            int idx = base + i;
            if (idx >= P) break;
            while (s < NSEG - 1 && idx >= off_next) {
                if (acc != 0.f) atomicAdd(&bsum[s], acc);
                acc = 0.f; ++s; off_next = off[s + 1];
            }
            acc += pair_e(atomd, pairs[2 * (size_t)idx], pairs[2 * (size_t)idx + 1]);
        }
        if (acc != 0.f) atomicAdd(&bsum[s], acc);
    }
    __syncthreads();
    // direct device-scope atomic accumulation into d_out (zeroed by k_mm);
    // 256 blocks x 64 addresses, ulp-level ordering noise vs 8.8e16 threshold
    if (tid < NSEG) atomicAdd(&out[tid], bsum[tid]);
}

extern "C" void kernel_launch(void* const* d_in, const int* in_sizes, int n_in,
                              void* d_out, int out_size, void* d_ws, size_t ws_size,
                              hipStream_t stream)
{
    const float* r    = (const float*)d_in[0];
    const float* xyz  = (const float*)d_in[1];
    const int*   prs  = (const int*)d_in[2];
    const int*   np   = (const int*)d_in[3];
    const float* sW1  = (const float*)d_in[4];
    const float* sb1  = (const float*)d_in[5];
    const float* sW2  = (const float*)d_in[6];
    const float* sb2  = (const float*)d_in[7];
    const float* sW3  = (const float*)d_in[8];
    const float* sb3  = (const float*)d_in[9];
    const float* eW1  = (const float*)d_in[10];
    const float* eb1  = (const float*)d_in[11];
    const float* eW2  = (const float*)d_in[12];
    const float* eb2  = (const float*)d_in[13];
    const float* eW3  = (const float*)d_in[14];
    const float* eb3  = (const float*)d_in[15];
    float* out = (float*)d_out;
    const int P = in_sizes[2] / 2;

    float4* atomd = (float4*)d_ws;               // 8192 float4 = 128 KB

    size_t smem1 = 131072 + 512;
    hipFuncSetAttribute((const void*)k_mm, hipFuncAttributeMaxDynamicSharedMemorySize, (int)smem1);
    k_mm<<<NATOM / 64, 512, smem1, stream>>>(r, xyz, sW1, sb1, sW2, sb2, sW3, sb3,
                                             eW1, eb1, eW2, eb2, eW3, eb3, atomd, out);

    size_t smem = (size_t)NATOM * 16 + 68 * 4 + NSEG * 4;   // 131,600 B
    hipFuncSetAttribute((const void*)k_pair, hipFuncAttributeMaxDynamicSharedMemorySize, (int)smem);
    k_pair<<<PB, PT, smem, stream>>>(atomd, prs, np, out, P);
}